// Round 1
// baseline (4403.714 us; speedup 1.0000x reference)
//
#include <hip/hip_runtime.h>
#include <hip/hip_bf16.h>

#define C_DIM 2048
#define H_DIM 48
#define W_DIM 96
#define N_DIM 4
#define HW    (H_DIM * W_DIM)     /* 4608 */
#define NJ    (N_DIM * W_DIM)     /* 384  */
#define KH_MID 4

#define NB     256                /* 64 o-groups x 4 n; 1 block/CU (LDS-bound) */
#define NT     384                /* 6 waves: (jt 0..2) x (kh 0..1)            */
#define BO     32                 /* o-rows per block; W slice 128 KB in LDS   */
#define SLDS   100                /* epilogue zone row stride (floats); 400B   */
#define NSTEP  (2 * H_DIM - 2)    /* 94 recurrence steps                        */

typedef __bf16 bf16x8 __attribute__((ext_vector_type(8)));
typedef float  floatx4 __attribute__((ext_vector_type(4)));

__device__ __forceinline__ void gload_lds16(const __hip_bfloat16* g, __hip_bfloat16* l) {
    __builtin_amdgcn_global_load_lds(
        (const __attribute__((address_space(1))) void*)g,
        (__attribute__((address_space(3))) void*)l, 16, 0, 0);
}

// Device-scope grid barrier (sense = monotone target). __threadfence() at agent
// scope emits the L2 writeback/invalidate needed for cross-XCD carry visibility.
__device__ __forceinline__ void gbar(unsigned* cnt, unsigned target) {
    __syncthreads();
    if (threadIdx.x == 0) {
        __threadfence();                       // release: flush this XCD's L2
        atomicAdd(cnt, 1u);                    // device-scope by default
        while (__hip_atomic_load(cnt, __ATOMIC_RELAXED, __HIP_MEMORY_SCOPE_AGENT) < target)
            __builtin_amdgcn_s_sleep(2);
        __threadfence();                       // acquire: invalidate L1/L2
    }
    __syncthreads();
}

// Pack middle tap W[:,:,4,0] -> bf16 image in the exact linear order the fused
// kernel stages into LDS: per og (64): granule (kk 0..63)(o 0..31)(q 0..3)(e 0..7)
// holding W[o0+o][kk*32 + q*8 + e].  k-major layout => ds_read_b128 of MFMA
// B-fragments is bank-conflict-free with zero address swizzling.
__global__ void pack_w(const float* __restrict__ W, __hip_bfloat16* __restrict__ Wimg) {
    int i  = blockIdx.x * blockDim.x + threadIdx.x;   // over 64*32*2048
    int c  = i & 2047;
    int r  = (i >> 11) & 31;
    int og = i >> 16;
    float v = W[((size_t)(og * BO + r) * C_DIM + c) * 9 + KH_MID];
    int kk = c >> 5, qq = (c >> 3) & 3, e = c & 7;
    Wimg[(size_t)og * 65536 + kk * 1024 + r * 32 + qq * 8 + e] = __float2bfloat16(v);
}

// down[0] = fea[:,:,0,:]; pack carry0[j][c] bf16 (j = n*W + w); reset barrier.
__global__ void init_carry(const float* __restrict__ fea, float* __restrict__ outp,
                           __hip_bfloat16* __restrict__ carry0, unsigned* __restrict__ barcnt) {
    int i = blockIdx.x * blockDim.x + threadIdx.x;   // over N*C*W
    if (i == 0) *barcnt = 0;
    int w  = i % W_DIM;
    int nc = i / W_DIM;            // n*C + c
    int c  = nc % C_DIM;
    int n  = nc / C_DIM;
    float v = fea[(size_t)nc * HW + w];   // h = 0
    outp[(size_t)nc * HW + w] = v;
    carry0[(n * W_DIM + w) * C_DIM + c] = __float2bfloat16(v);
}

// One persistent cooperative kernel runs all 94 recurrence steps.
// Block (og, n): owns o-slice [o0,o0+32) and all 96 w of batch n.
// W slice lives in LDS for the whole kernel (staged once).
// Wave (jt, kh): computes 32o x 32j over K-half kh (2x2 16x16x32 fragments).
// K-halves summed in the LDS epilogue zone, which also transposes so that
// out (f32) and carry (bf16) stores are fully coalesced.
__global__ __launch_bounds__(NT, 1) void fused_all(
    const __hip_bfloat16* __restrict__ Wimg,
    __hip_bfloat16* __restrict__ carryA,
    __hip_bfloat16* __restrict__ carryB,
    const float* __restrict__ bias,
    const float* fea,            // no restrict: resid aliases out in pass 2
    float* out,
    unsigned* barcnt)
{
    __shared__ __hip_bfloat16 Wl[64 * 1024];   // 128 KB, k-major granules
    __shared__ float zone[2][BO][SLDS];        // 25 KB reduce/transpose zone

    const int id = blockIdx.x;
    const int og = id & 63;        // id%8 -> XCD
    const int n  = id >> 6;        // 0..3
    const int o0 = og * BO;
    const int j0 = n * W_DIM;

    const int tid  = threadIdx.x;
    const int wv   = tid >> 6;
    const int lane = tid & 63;
    const int c16  = lane & 15;
    const int q    = lane >> 4;
    const int jt   = wv % 3;       // j-tile (32 rows)
    const int kh   = wv / 3;       // K half (1024)

    // ---- stage W slice once: 128 segments x 1 KB, linear copy ----
    for (int sg = wv; sg < 128; sg += 6)
        gload_lds16(Wimg + (size_t)og * 65536 + sg * 512 + lane * 8, Wl + sg * 512);

    // ---- hoisted addressing ----
    // A (carry) per-lane: row j0 + jt*32 + ji*16 + c16, k = kh*1024 + kk*32 + q*8
    const size_t arow0 = (size_t)(j0 + jt * 32 + c16) * C_DIM + kh * 1024 + q * 8;
    // B (W in LDS), element index: kk-major granules
    const int bE = kh * 32768 + c16 * 32 + q * 8;      // + oi*512 + kk*1024

    // phase 2 (out store): thread -> (o_l, 8 consecutive w)
    const int oL = tid / 12;
    const int wq = tid % 12;
    const int w2 = wq * 8;
    const float bo = bias[o0 + oL];
    const size_t obase0 = (size_t)(n * C_DIM + o0 + oL) * HW + w2;

    // phase 3 (carry store): thread -> (w row, 8 consecutive o)
    const int wr = tid >> 2;
    const int oq = tid & 3;
    const size_t cidx = (size_t)(j0 + wr) * C_DIM + o0 + oq * 8;

    __syncthreads();   // staged W visible (compiler drains vmcnt)

    unsigned target = 0;
    for (int s = 0; s < NSTEP; ++s) {
        const int h = (s < H_DIM - 1) ? (s + 1) : (2 * H_DIM - 3 - s);  // 1..47, then 46..0
        const float* resid = (s < H_DIM - 1) ? fea : out;
        const __hip_bfloat16* csrc = (s & 1) ? carryB : carryA;
        __hip_bfloat16*       cdst = (s & 1) ? carryA : carryB;

        const __hip_bfloat16* ap0 = csrc + arow0;
        const __hip_bfloat16* ap1 = ap0 + 16 * C_DIM;

        floatx4 a00 = {0.f, 0.f, 0.f, 0.f};
        floatx4 a01 = a00, a10 = a00, a11 = a00;
        #pragma unroll 8
        for (int kk = 0; kk < 32; ++kk) {
            bf16x8 av0 = *(const bf16x8*)(ap0 + kk * 32);
            bf16x8 av1 = *(const bf16x8*)(ap1 + kk * 32);
            bf16x8 bv0 = *(const bf16x8*)(Wl + bE + kk * 1024);
            bf16x8 bv1 = *(const bf16x8*)(Wl + bE + 512 + kk * 1024);
            a00 = __builtin_amdgcn_mfma_f32_16x16x32_bf16(av0, bv0, a00, 0, 0, 0);
            a01 = __builtin_amdgcn_mfma_f32_16x16x32_bf16(av0, bv1, a01, 0, 0, 0);
            a10 = __builtin_amdgcn_mfma_f32_16x16x32_bf16(av1, bv0, a10, 0, 0, 0);
            a11 = __builtin_amdgcn_mfma_f32_16x16x32_bf16(av1, bv1, a11, 0, 0, 0);
        }

        // ---- dump fragments: D row(M=j)=q*4+r, col(N=o)=c16; r is contiguous w ----
        {
            const int w0 = jt * 32 + q * 4;
            *(floatx4*)&zone[kh][c16][w0]           = a00;   // ji=0, oi=0
            *(floatx4*)&zone[kh][16 + c16][w0]      = a01;   // ji=0, oi=1
            *(floatx4*)&zone[kh][c16][w0 + 16]      = a10;   // ji=1, oi=0
            *(floatx4*)&zone[kh][16 + c16][w0 + 16] = a11;   // ji=1, oi=1
        }
        __syncthreads();

        // ---- phase 2: sum K-halves, bias+relu+residual, coalesced out store ----
        {
            const size_t ob = obase0 + (size_t)h * W_DIM;
            floatx4 z0a = *(const floatx4*)&zone[0][oL][w2];
            floatx4 z0b = *(const floatx4*)&zone[0][oL][w2 + 4];
            floatx4 z1a = *(const floatx4*)&zone[1][oL][w2];
            floatx4 z1b = *(const floatx4*)&zone[1][oL][w2 + 4];
            floatx4 ra  = *(const floatx4*)(resid + ob);
            floatx4 rb  = *(const floatx4*)(resid + ob + 4);
            floatx4 va, vb;
            #pragma unroll
            for (int e = 0; e < 4; ++e) {
                va[e] = fmaxf(z0a[e] + z1a[e] + bo, 0.f) + ra[e];
                vb[e] = fmaxf(z0b[e] + z1b[e] + bo, 0.f) + rb[e];
            }
            *(floatx4*)(out + ob)     = va;
            *(floatx4*)(out + ob + 4) = vb;
            // write final values back (own slots only) for the carry transpose
            *(floatx4*)&zone[0][oL][w2]     = va;
            *(floatx4*)&zone[0][oL][w2 + 4] = vb;
        }
        __syncthreads();

        // ---- phase 3: transpose to carry[j][o], coalesced 16B bf16 stores ----
        {
            alignas(16) __hip_bfloat16 hb[8];
            #pragma unroll
            for (int k = 0; k < 8; ++k)
                hb[k] = __float2bfloat16(zone[0][oq * 8 + k][wr]);
            *(bf16x8*)(cdst + cidx) = *(const bf16x8*)hb;
        }

        target += NB;
        if (s + 1 < NSTEP) gbar(barcnt, target);
    }
}

extern "C" void kernel_launch(void* const* d_in, const int* in_sizes, int n_in,
                              void* d_out, int out_size, void* d_ws, size_t ws_size,
                              hipStream_t stream) {
    const float* fea = (const float*)d_in[0];
    const float* W   = (const float*)d_in[1];
    const float* b   = (const float*)d_in[2];
    float* out = (float*)d_out;

    __hip_bfloat16* Wimg   = (__hip_bfloat16*)d_ws;                 // 8 MB
    __hip_bfloat16* carryA = Wimg + (size_t)C_DIM * C_DIM;          // 1.5 MB
    __hip_bfloat16* carryB = carryA + (size_t)NJ * C_DIM;           // 1.5 MB
    unsigned* barcnt = (unsigned*)(carryB + (size_t)NJ * C_DIM);

    hipLaunchKernelGGL(pack_w, dim3((64 * BO * C_DIM) / 256), dim3(256), 0, stream, W, Wimg);
    hipLaunchKernelGGL(init_carry, dim3((N_DIM * C_DIM * W_DIM) / 256), dim3(256), 0, stream,
                       fea, out, carryA, barcnt);

    void* args[] = { (void*)&Wimg, (void*)&carryA, (void*)&carryB,
                     (void*)&b, (void*)&fea, (void*)&out, (void*)&barcnt };
    hipLaunchCooperativeKernel(fused_all, dim3(NB), dim3(NT), args, 0, stream);
}

// Round 2
// 2580.671 us; speedup vs baseline: 1.7064x; 1.7064x over previous
//
#include <hip/hip_runtime.h>
#include <hip/hip_bf16.h>

#define C_DIM 2048
#define H_DIM 48
#define W_DIM 96
#define N_DIM 4
#define HW    (H_DIM * W_DIM)     /* 4608 */
#define NJ    (N_DIM * W_DIM)     /* 384  */
#define KH_MID 4

#define NB     256                /* 64 o-groups x 4 n; 1 block/CU (LDS-bound) */
#define NT     384                /* 6 waves: (jt 0..2) x (kh 0..1)            */
#define BO     32                 /* o-rows per block; W slice 128 KB in LDS   */
#define SLDS   100                /* epilogue zone row stride (floats); 400B   */
#define NSTEP  (2 * H_DIM - 2)    /* 94 recurrence steps                        */

typedef __bf16 bf16x8 __attribute__((ext_vector_type(8)));
typedef float  floatx4 __attribute__((ext_vector_type(4)));

__device__ __forceinline__ void gload_lds16(const __hip_bfloat16* g, __hip_bfloat16* l) {
    __builtin_amdgcn_global_load_lds(
        (const __attribute__((address_space(1))) void*)g,
        (__attribute__((address_space(3))) void*)l, 16, 0, 0);
}

// Device-scope (MALL) write-through 16B store: visible to other XCDs without
// any buffer_wbl2. This is how LLVM lowers agent-scope atomic stores.
__device__ __forceinline__ void store16_sc1(__hip_bfloat16* p, floatx4 v) {
    asm volatile("global_store_dwordx4 %0, %1, off sc1" :: "v"(p), "v"(v) : "memory");
}

// Grid barrier, targeted-coherence version.
// Release side: carry was stored sc1 (already at MALL); each wave drains its own
// vmcnt before __syncthreads, so thread0's arrival add is ordered after them.
// Acquire side: one agent acquire fence = buffer_inv (clean invalidate, NO
// writeback walk) so cacheable carry loads refetch fresh lines from the MALL.
__device__ __forceinline__ void gbar(unsigned* cnt, unsigned target) {
    __syncthreads();
    if (threadIdx.x == 0) {
        __hip_atomic_fetch_add(cnt, 1u, __ATOMIC_RELAXED, __HIP_MEMORY_SCOPE_AGENT);
        while (__hip_atomic_load(cnt, __ATOMIC_RELAXED, __HIP_MEMORY_SCOPE_AGENT) < target)
            __builtin_amdgcn_s_sleep(2);
        __builtin_amdgcn_fence(__ATOMIC_ACQUIRE, "agent");   // buffer_inv
    }
    __syncthreads();
}

// Pack middle tap W[:,:,4,0] -> bf16 in MFMA-fragment order so that the fused
// kernel's B ds_read_b128 is LANE-LINEAR (lane l reads bytes [l*16, l*16+16) of
// a 1 KB fragment block => 16 lanes/phase cover exactly one 256 B LDS clock,
// bank-conflict-free).  Element index E within an og-slice (65536 elems):
//   E = K*1024 + oi*512 + q*128 + c16*8 + e
// holds Wm[og*32 + oi*16 + c16][K*32 + q*8 + e].
__global__ void pack_w(const float* __restrict__ W, __hip_bfloat16* __restrict__ Wimg) {
    int i  = blockIdx.x * blockDim.x + threadIdx.x;   // over 64*65536
    int og = i >> 16;
    int E  = i & 65535;
    int e   = E & 7;
    int c16 = (E >> 3) & 15;
    int q   = (E >> 7) & 3;
    int oi  = (E >> 9) & 1;
    int K   = E >> 10;
    int o = og * BO + oi * 16 + c16;
    int c = K * 32 + q * 8 + e;
    Wimg[i] = __float2bfloat16(W[((size_t)o * C_DIM + c) * 9 + KH_MID]);
}

// down[0] = fea[:,:,0,:]; pack carry0[j][c] bf16 (j = n*W + w); reset barrier.
__global__ void init_carry(const float* __restrict__ fea, float* __restrict__ outp,
                           __hip_bfloat16* __restrict__ carry0, unsigned* __restrict__ barcnt) {
    int i = blockIdx.x * blockDim.x + threadIdx.x;   // over N*C*W
    if (i == 0) *barcnt = 0;
    int w  = i % W_DIM;
    int nc = i / W_DIM;            // n*C + c
    int c  = nc % C_DIM;
    int n  = nc / C_DIM;
    float v = fea[(size_t)nc * HW + w];   // h = 0
    outp[(size_t)nc * HW + w] = v;
    carry0[(n * W_DIM + w) * C_DIM + c] = __float2bfloat16(v);
}

// One persistent cooperative kernel runs all 94 recurrence steps.
// Block (og, n): owns o-slice [o0,o0+32) and all 96 w of batch n.
// W slice lives in LDS for the whole kernel (staged once, fragment-order).
// Wave (jt, kh): computes 32o x 32j over K-half kh (2x2 16x16x32 fragments).
// K-halves summed in the LDS epilogue zone, which also transposes so that
// out (f32) and carry (bf16, sc1) stores are fully coalesced.
__global__ __launch_bounds__(NT, 1) void fused_all(
    const __hip_bfloat16* __restrict__ Wimg,
    __hip_bfloat16* __restrict__ carryA,
    __hip_bfloat16* __restrict__ carryB,
    const float* __restrict__ bias,
    const float* fea,            // no restrict: resid aliases out in pass 2
    float* out,
    unsigned* barcnt)
{
    __shared__ __hip_bfloat16 Wl[64 * 1024];   // 128 KB, fragment-order
    __shared__ float zone[2][BO][SLDS];        // 25 KB reduce/transpose zone

    const int id = blockIdx.x;
    const int og = id & 63;        // id%8 -> XCD
    const int n  = id >> 6;        // 0..3
    const int o0 = og * BO;
    const int j0 = n * W_DIM;

    const int tid  = threadIdx.x;
    const int wv   = tid >> 6;
    const int lane = tid & 63;
    const int c16  = lane & 15;
    const int q    = lane >> 4;
    const int jt   = wv % 3;       // j-tile (32 rows)
    const int kh   = wv / 3;       // K half (1024)

    // ---- stage W slice once: 128 segments x 1 KB, linear copy ----
    for (int sg = wv; sg < 128; sg += 6)
        gload_lds16(Wimg + (size_t)og * 65536 + sg * 512 + lane * 8, Wl + sg * 512);

    // ---- hoisted addressing ----
    // A (carry) per-lane: row j0 + jt*32 + ji*16 + c16, k = kh*1024 + kk*32 + q*8
    const size_t arow0 = (size_t)(j0 + jt * 32 + c16) * C_DIM + kh * 1024 + q * 8;
    // B (W in LDS): lane-linear fragment blocks
    const __hip_bfloat16* Wb = Wl + kh * 32768 + lane * 8;

    // phase 2 (out store): thread -> (o_l, 8 consecutive w)
    const int oL = tid / 12;
    const int wq = tid % 12;
    const int w2 = wq * 8;
    const float bo = bias[o0 + oL];
    const size_t obase0 = (size_t)(n * C_DIM + o0 + oL) * HW + w2;

    // phase 3 (carry store): thread -> (w row, 8 consecutive o)
    const int wr = tid >> 2;
    const int oq = tid & 3;
    const size_t cidx = (size_t)(j0 + wr) * C_DIM + o0 + oq * 8;

    __syncthreads();   // staged W visible (compiler drains vmcnt)

    unsigned target = 0;
    for (int s = 0; s < NSTEP; ++s) {
        const int h = (s < H_DIM - 1) ? (s + 1) : (2 * H_DIM - 3 - s);  // 1..47, then 46..0
        const float* resid = (s < H_DIM - 1) ? fea : out;
        const __hip_bfloat16* csrc = (s & 1) ? carryB : carryA;
        __hip_bfloat16*       cdst = (s & 1) ? carryA : carryB;

        const __hip_bfloat16* ap0 = csrc + arow0;
        const __hip_bfloat16* ap1 = ap0 + 16 * C_DIM;

        floatx4 a00 = {0.f, 0.f, 0.f, 0.f};
        floatx4 a01 = a00, a10 = a00, a11 = a00;
        #pragma unroll 8
        for (int kk = 0; kk < 32; ++kk) {
            bf16x8 av0 = *(const bf16x8*)(ap0 + kk * 32);
            bf16x8 av1 = *(const bf16x8*)(ap1 + kk * 32);
            bf16x8 bv0 = *(const bf16x8*)(Wb + kk * 1024);
            bf16x8 bv1 = *(const bf16x8*)(Wb + kk * 1024 + 512);
            a00 = __builtin_amdgcn_mfma_f32_16x16x32_bf16(av0, bv0, a00, 0, 0, 0);
            a01 = __builtin_amdgcn_mfma_f32_16x16x32_bf16(av0, bv1, a01, 0, 0, 0);
            a10 = __builtin_amdgcn_mfma_f32_16x16x32_bf16(av1, bv0, a10, 0, 0, 0);
            a11 = __builtin_amdgcn_mfma_f32_16x16x32_bf16(av1, bv1, a11, 0, 0, 0);
        }

        // ---- dump fragments: D row(M=j)=q*4+r, col(N=o)=c16; r is contiguous w ----
        {
            const int w0 = jt * 32 + q * 4;
            *(floatx4*)&zone[kh][c16][w0]           = a00;   // ji=0, oi=0
            *(floatx4*)&zone[kh][16 + c16][w0]      = a01;   // ji=0, oi=1
            *(floatx4*)&zone[kh][c16][w0 + 16]      = a10;   // ji=1, oi=0
            *(floatx4*)&zone[kh][16 + c16][w0 + 16] = a11;   // ji=1, oi=1
        }
        __syncthreads();

        // ---- phase 2: sum K-halves, bias+relu+residual, coalesced out store ----
        {
            const size_t ob = obase0 + (size_t)h * W_DIM;
            floatx4 z0a = *(const floatx4*)&zone[0][oL][w2];
            floatx4 z0b = *(const floatx4*)&zone[0][oL][w2 + 4];
            floatx4 z1a = *(const floatx4*)&zone[1][oL][w2];
            floatx4 z1b = *(const floatx4*)&zone[1][oL][w2 + 4];
            floatx4 ra  = *(const floatx4*)(resid + ob);
            floatx4 rb  = *(const floatx4*)(resid + ob + 4);
            floatx4 va, vb;
            #pragma unroll
            for (int e = 0; e < 4; ++e) {
                va[e] = fmaxf(z0a[e] + z1a[e] + bo, 0.f) + ra[e];
                vb[e] = fmaxf(z0b[e] + z1b[e] + bo, 0.f) + rb[e];
            }
            *(floatx4*)(out + ob)     = va;
            *(floatx4*)(out + ob + 4) = vb;
            // write final values back (own slots only) for the carry transpose
            *(floatx4*)&zone[0][oL][w2]     = va;
            *(floatx4*)&zone[0][oL][w2 + 4] = vb;
        }
        __syncthreads();

        // ---- phase 3: transpose to carry[j][o], coalesced 16B sc1 stores ----
        {
            alignas(16) __hip_bfloat16 hb[8];
            #pragma unroll
            for (int k = 0; k < 8; ++k)
                hb[k] = __float2bfloat16(zone[0][oq * 8 + k][wr]);
            store16_sc1(cdst + cidx, *(const floatx4*)hb);
            asm volatile("s_waitcnt vmcnt(0)" ::: "memory");   // sc1 stores acked at MALL
        }

        target += NB;
        if (s + 1 < NSTEP) gbar(barcnt, target);
    }
}

extern "C" void kernel_launch(void* const* d_in, const int* in_sizes, int n_in,
                              void* d_out, int out_size, void* d_ws, size_t ws_size,
                              hipStream_t stream) {
    const float* fea = (const float*)d_in[0];
    const float* W   = (const float*)d_in[1];
    const float* b   = (const float*)d_in[2];
    float* out = (float*)d_out;

    __hip_bfloat16* Wimg   = (__hip_bfloat16*)d_ws;                 // 8 MB
    __hip_bfloat16* carryA = Wimg + (size_t)C_DIM * C_DIM;          // 1.5 MB
    __hip_bfloat16* carryB = carryA + (size_t)NJ * C_DIM;           // 1.5 MB
    unsigned* barcnt = (unsigned*)(carryB + (size_t)NJ * C_DIM);

    hipLaunchKernelGGL(pack_w, dim3((64 * BO * C_DIM) / 256), dim3(256), 0, stream, W, Wimg);
    hipLaunchKernelGGL(init_carry, dim3((N_DIM * C_DIM * W_DIM) / 256), dim3(256), 0, stream,
                       fea, out, carryA, barcnt);

    void* args[] = { (void*)&Wimg, (void*)&carryA, (void*)&carryB,
                     (void*)&b, (void*)&fea, (void*)&out, (void*)&barcnt };
    hipLaunchCooperativeKernel(fused_all, dim3(NB), dim3(NT), args, 0, stream);
}

// Round 4
// 2002.953 us; speedup vs baseline: 2.1986x; 1.2884x over previous
//
#include <hip/hip_runtime.h>
#include <hip/hip_bf16.h>

#define C_DIM 2048
#define H_DIM 48
#define W_DIM 96
#define N_DIM 4
#define HW    (H_DIM * W_DIM)     /* 4608 */
#define NJ    (N_DIM * W_DIM)     /* 384  */
#define KH_MID 4

#define NB     256                /* 64 o-groups x 4 n; 1 block/CU (LDS-bound) */
#define NT     768                /* 12 waves: (jt 0..5) x (kh 0..1)           */
#define BO     32                 /* o-rows per block; W slice 128 KB in LDS   */
#define SLDS   101                /* zone row stride (odd -> conflict-free-ish)*/
#define NSTEP  (2 * H_DIM - 2)    /* 94 recurrence steps                       */
#define NRING  (NSTEP + 1)        /* 95 virgin carry buffers (write-once)      */
#define CE     (NJ * C_DIM)       /* carry elems per buffer: 786432 (1.5 MB)   */

typedef __bf16 bf16x8 __attribute__((ext_vector_type(8)));
typedef float  floatx4 __attribute__((ext_vector_type(4)));
typedef int    intx2   __attribute__((ext_vector_type(2)));

__device__ __forceinline__ void gload_lds16(const __hip_bfloat16* g, __hip_bfloat16* l) {
    __builtin_amdgcn_global_load_lds(
        (const __attribute__((address_space(1))) void*)g,
        (__attribute__((address_space(3))) void*)l, 16, 0, 0);
}

// Device-scope (MALL) write-through 8B store: other XCDs' cold misses see it.
__device__ __forceinline__ void store8_sc1(__hip_bfloat16* p, intx2 v) {
    asm volatile("global_store_dwordx2 %0, %1, off sc0 sc1" :: "v"(p), "v"(v) : "memory");
}

// Grid barrier. Virgin-ring mode needs NO fence: carry stores are sc1
// write-through (MALL authoritative) and next step's reads are cold misses
// (addresses never touched this launch). Fallback (ping-pong) mode keeps the
// agent acquire fence (buffer_inv) for stale-line safety.
__device__ __forceinline__ void gbar(unsigned* cnt, unsigned target, int virgin) {
    __syncthreads();   // compiler drains vmcnt(0) here -> sc1 stores acked at MALL
    if (threadIdx.x == 0) {
        __hip_atomic_fetch_add(cnt, 1u, __ATOMIC_RELAXED, __HIP_MEMORY_SCOPE_AGENT);
        while (__hip_atomic_load(cnt, __ATOMIC_RELAXED, __HIP_MEMORY_SCOPE_AGENT) < target)
            __builtin_amdgcn_s_sleep(2);
        if (!virgin)
            __builtin_amdgcn_fence(__ATOMIC_ACQUIRE, "agent");   // buffer_inv
    }
    __syncthreads();
}

// Pack middle tap W[:,:,4,0] -> bf16 in MFMA-fragment order (lane-linear B
// ds_read_b128, bank-conflict-free). E within an og-slice (65536 elems):
//   E = K*1024 + oi*512 + q*128 + c16*8 + e  holds  Wm[og*32+oi*16+c16][K*32+q*8+e]
__global__ void pack_w(const float* __restrict__ W, __hip_bfloat16* __restrict__ Wimg) {
    int i  = blockIdx.x * blockDim.x + threadIdx.x;   // over 64*65536
    int og = i >> 16;
    int E  = i & 65535;
    int e   = E & 7;
    int c16 = (E >> 3) & 15;
    int q   = (E >> 7) & 3;
    int oi  = (E >> 9) & 1;
    int K   = E >> 10;
    int o = og * BO + oi * 16 + c16;
    int c = K * 32 + q * 8 + e;
    Wimg[i] = __float2bfloat16(W[((size_t)o * C_DIM + c) * 9 + KH_MID]);
}

// down[0] = fea[:,:,0,:]; pack carry0[j][c] bf16 (j = n*W + w); reset barrier.
__global__ void init_carry(const float* __restrict__ fea, float* __restrict__ outp,
                           __hip_bfloat16* __restrict__ carry0, unsigned* __restrict__ barcnt) {
    int i = blockIdx.x * blockDim.x + threadIdx.x;   // over N*C*W
    if (i == 0) *barcnt = 0;
    int w  = i % W_DIM;
    int nc = i / W_DIM;            // n*C + c
    int c  = nc % C_DIM;
    int n  = nc / C_DIM;
    float v = fea[(size_t)nc * HW + w];   // h = 0
    outp[(size_t)nc * HW + w] = v;
    carry0[(n * W_DIM + w) * C_DIM + c] = __float2bfloat16(v);
}

// Persistent cooperative kernel, all 94 steps.
// Block (og, n): o-slice [o0,o0+32), all 96 w of batch n. W slice in LDS forever.
// Wave (jt 0..5, kh 0..1): 16j x 32o over K-half kh; one A-load feeds 2 MFMAs.
// Carry ring: step s reads ring[s], writes ring[s+1] (virgin -> L2-cacheable
// reads shared by the 8 same-n blocks per XCD, no fences).
__global__ __launch_bounds__(NT) void fused_all(
    const __hip_bfloat16* __restrict__ Wimg,
    __hip_bfloat16* __restrict__ ring,      // NRING buffers (virgin mode)
    __hip_bfloat16* __restrict__ carryA,    // fallback ping-pong
    __hip_bfloat16* __restrict__ carryB,
    const float* __restrict__ bias,
    const float* fea,            // no restrict: resid aliases out in pass 2
    float* out,
    unsigned* barcnt,
    int virgin)
{
    __shared__ __hip_bfloat16 Wl[64 * 1024];   // 128 KB, fragment-order
    __shared__ float zone[2][BO][SLDS];        // 25.9 KB reduce/transpose zone

    const int id = blockIdx.x;
    const int og = id & 63;        // id%8 -> XCD; all 4 n of an og share an XCD
    const int n  = id >> 6;        // 0..3
    const int o0 = og * BO;
    const int j0 = n * W_DIM;

    const int tid  = threadIdx.x;
    const int wv   = tid >> 6;
    const int lane = tid & 63;
    const int c16  = lane & 15;
    const int q    = lane >> 4;
    const int jt   = wv % 6;       // j-tile (16 rows)
    const int kh   = wv / 6;       // K half (1024)

    // ---- stage W slice once: 128 segments x 1 KB, linear copy ----
    for (int sg = wv; sg < 128; sg += 12)
        gload_lds16(Wimg + (size_t)og * 65536 + sg * 512 + lane * 8, Wl + sg * 512);

    // ---- hoisted addressing ----
    const size_t arow = (size_t)(j0 + jt * 16 + c16) * C_DIM + kh * 1024 + q * 8;
    const __hip_bfloat16* Wb = Wl + kh * 32768 + lane * 8;

    // phase 2 (out store): thread -> (o_l, 4 consecutive w)
    const int oL = tid / 24;
    const int wq = tid % 24;
    const int w2 = wq * 4;
    const float bo = bias[o0 + oL];
    const size_t obase0 = (size_t)(n * C_DIM + o0 + oL) * HW + w2;

    // phase 3 (carry store): thread -> (w row, 4 consecutive o)
    const int wr = tid >> 3;       // 0..95
    const int oq = tid & 7;        // 0..7
    const size_t cidx = (size_t)(j0 + wr) * C_DIM + o0 + oq * 4;

    __syncthreads();   // staged W visible

    unsigned target = 0;
    for (int s = 0; s < NSTEP; ++s) {
        const int h = (s < H_DIM - 1) ? (s + 1) : (2 * H_DIM - 3 - s);  // 1..47, 46..0
        const float* resid = (s < H_DIM - 1) ? fea : out;
        const __hip_bfloat16* csrc;
        __hip_bfloat16*       cdst;
        if (virgin) { csrc = ring + (size_t)s * CE; cdst = ring + (size_t)(s + 1) * CE; }
        else        { csrc = (s & 1) ? carryB : carryA; cdst = (s & 1) ? carryA : carryB; }

        // prefetch residual before compute (latency hides under MFMA loop)
        const floatx4 rv = *(const floatx4*)(resid + obase0 + (size_t)h * W_DIM);

        const __hip_bfloat16* ap = csrc + arow;
        floatx4 a0 = {0.f, 0.f, 0.f, 0.f};
        floatx4 a1 = a0;
        #pragma unroll 8
        for (int kk = 0; kk < 32; ++kk) {
            bf16x8 av  = *(const bf16x8*)(ap + kk * 32);
            bf16x8 bv0 = *(const bf16x8*)(Wb + kk * 1024);
            bf16x8 bv1 = *(const bf16x8*)(Wb + kk * 1024 + 512);
            a0 = __builtin_amdgcn_mfma_f32_16x16x32_bf16(av, bv0, a0, 0, 0, 0);
            a1 = __builtin_amdgcn_mfma_f32_16x16x32_bf16(av, bv1, a1, 0, 0, 0);
        }

        // ---- dump fragments: D row(M=j)=q*4+r, col(N=o)=c16 ----
        {
            const int w0 = jt * 16 + q * 4;
            *(floatx4*)&zone[kh][c16][w0]      = a0;   // oi=0
            *(floatx4*)&zone[kh][16 + c16][w0] = a1;   // oi=1
        }
        __syncthreads();

        // ---- phase 2: sum K-halves, bias+relu+residual, coalesced out store ----
        {
            const size_t ob = obase0 + (size_t)h * W_DIM;
            floatx4 z0 = *(const floatx4*)&zone[0][oL][w2];
            floatx4 z1 = *(const floatx4*)&zone[1][oL][w2];
            floatx4 va;
            #pragma unroll
            for (int e = 0; e < 4; ++e)
                va[e] = fmaxf(z0[e] + z1[e] + bo, 0.f) + rv[e];
            *(floatx4*)(out + ob) = va;
            *(floatx4*)&zone[0][oL][w2] = va;   // final values for the transpose
        }
        __syncthreads();

        // ---- phase 3: transpose to carry[j][o], coalesced 8B sc1 stores ----
        {
            alignas(8) __hip_bfloat16 hb[4];
            #pragma unroll
            for (int k = 0; k < 4; ++k)
                hb[k] = __float2bfloat16(zone[0][oq * 4 + k][wr]);
            store8_sc1(cdst + cidx, *(const intx2*)hb);
        }

        target += NB;
        if (s + 1 < NSTEP) gbar(barcnt, target, virgin);
    }
}

extern "C" void kernel_launch(void* const* d_in, const int* in_sizes, int n_in,
                              void* d_out, int out_size, void* d_ws, size_t ws_size,
                              hipStream_t stream) {
    const float* fea = (const float*)d_in[0];
    const float* W   = (const float*)d_in[1];
    const float* b   = (const float*)d_in[2];
    float* out = (float*)d_out;

    __hip_bfloat16* Wimg   = (__hip_bfloat16*)d_ws;                 // 8 MB
    __hip_bfloat16* carryA = Wimg + (size_t)C_DIM * C_DIM;          // 1.5 MB
    __hip_bfloat16* carryB = carryA + (size_t)CE;                   // 1.5 MB
    unsigned* barcnt = (unsigned*)(carryB + (size_t)CE);
    __hip_bfloat16* ring   = (__hip_bfloat16*)((char*)barcnt + 256);

    const size_t need = ((size_t)C_DIM * C_DIM + 2 * (size_t)CE) * 2 + 256
                      + (size_t)NRING * CE * 2;
    const int virgin = (ws_size >= need) ? 1 : 0;
    __hip_bfloat16* carry0 = virgin ? ring : carryA;

    hipLaunchKernelGGL(pack_w, dim3((64 * BO * C_DIM) / 256), dim3(256), 0, stream, W, Wimg);
    hipLaunchKernelGGL(init_carry, dim3((N_DIM * C_DIM * W_DIM) / 256), dim3(256), 0, stream,
                       fea, out, carry0, barcnt);

    void* args[] = { (void*)&Wimg, (void*)&ring, (void*)&carryA, (void*)&carryB,
                     (void*)&b, (void*)&fea, (void*)&out, (void*)&barcnt, (void*)&virgin };
    hipLaunchCooperativeKernel(fused_all, dim3(NB), dim3(NT), args, 0, stream);
}

// Round 5
// 1601.633 us; speedup vs baseline: 2.7495x; 1.2506x over previous
//
#include <hip/hip_runtime.h>
#include <hip/hip_bf16.h>

#define C_DIM 2048
#define H_DIM 48
#define W_DIM 96
#define N_DIM 4
#define HW    (H_DIM * W_DIM)     /* 4608 */
#define NJ    (N_DIM * W_DIM)     /* 384  */
#define KH_MID 4

#define NB     256                /* 64 o-groups x 4 n; 1 block/CU (LDS-bound) */
#define NT     768                /* 12 waves: (jt 0..2) x (kq 0..3)           */
#define BO     32                 /* o-rows per block; W slice 128 KB in LDS   */
#define SLDS   101                /* zone row stride (floats)                  */
#define NSTEP  (2 * H_DIM - 2)    /* 94 recurrence steps                       */
#define NRING  (NSTEP + 1)        /* 95 virgin carry buffers (write-once)      */
#define CE     (NJ * C_DIM)       /* carry elems per buffer: 786432 (1.5 MB)   */

typedef __bf16 bf16x8 __attribute__((ext_vector_type(8)));
typedef float  floatx4 __attribute__((ext_vector_type(4)));
typedef int    intx2   __attribute__((ext_vector_type(2)));

__device__ __forceinline__ void gload_lds16(const __hip_bfloat16* g, __hip_bfloat16* l) {
    __builtin_amdgcn_global_load_lds(
        (const __attribute__((address_space(1))) void*)g,
        (__attribute__((address_space(3))) void*)l, 16, 0, 0);
}

// Device-scope (MALL) write-through 8B store: other XCDs' cold misses see it.
__device__ __forceinline__ void store8_sc1(__hip_bfloat16* p, intx2 v) {
    asm volatile("global_store_dwordx2 %0, %1, off sc0 sc1" :: "v"(p), "v"(v) : "memory");
}

// Fallback global barrier (ping-pong mode only): agent acquire fence after spin.
__device__ __forceinline__ void gbar(unsigned* cnt, unsigned target) {
    __syncthreads();
    if (threadIdx.x == 0) {
        __hip_atomic_fetch_add(cnt, 1u, __ATOMIC_RELAXED, __HIP_MEMORY_SCOPE_AGENT);
        while (__hip_atomic_load(cnt, __ATOMIC_RELAXED, __HIP_MEMORY_SCOPE_AGENT) < target)
            __builtin_amdgcn_s_sleep(2);
        __builtin_amdgcn_fence(__ATOMIC_ACQUIRE, "agent");   // buffer_inv
    }
    __syncthreads();
}

// Pack middle tap W[:,:,4,0] -> bf16 in MFMA-fragment order (lane-linear B
// ds_read_b128, bank-conflict-free). E within an og-slice (65536 elems):
//   E = K*1024 + oi*512 + q*128 + c16*8 + e  holds  Wm[og*32+oi*16+c16][K*32+q*8+e]
__global__ void pack_w(const float* __restrict__ W, __hip_bfloat16* __restrict__ Wimg) {
    int i  = blockIdx.x * blockDim.x + threadIdx.x;   // over 64*65536
    int og = i >> 16;
    int E  = i & 65535;
    int e   = E & 7;
    int c16 = (E >> 3) & 15;
    int q   = (E >> 7) & 3;
    int oi  = (E >> 9) & 1;
    int K   = E >> 10;
    int o = og * BO + oi * 16 + c16;
    int c = K * 32 + q * 8 + e;
    Wimg[i] = __float2bfloat16(W[((size_t)o * C_DIM + c) * 9 + KH_MID]);
}

// down[0] = fea[:,:,0,:]; pack carry0[j][c] bf16; zero barrier + per-n flags.
__global__ void init_carry(const float* __restrict__ fea, float* __restrict__ outp,
                           __hip_bfloat16* __restrict__ carry0, unsigned* __restrict__ sync) {
    int i = blockIdx.x * blockDim.x + threadIdx.x;   // over N*C*W
    if (i == 0) {
        sync[0] = 0;                       // fallback barrier counter
        for (int n = 0; n < N_DIM; ++n)    // per-n flags, 256B apart
            sync[64 + n * 64] = 0;
    }
    int w  = i % W_DIM;
    int nc = i / W_DIM;            // n*C + c
    int c  = nc % C_DIM;
    int n  = nc / C_DIM;
    float v = fea[(size_t)nc * HW + w];   // h = 0
    outp[(size_t)nc * HW + w] = v;
    carry0[(n * W_DIM + w) * C_DIM + c] = __float2bfloat16(v);
}

// Persistent cooperative kernel, all 94 steps.
// Block (og, n): o-slice [o0,o0+32), all 96 w of batch n. W slice in LDS forever.
// Wave (jt 0..2, kq 0..3): 32j x 32o over K-quarter kq (2x2 MFMA fragments;
// B fragments reused across 2 ji -> LDS B-traffic halved vs 16j waves).
// Sync (virgin mode): per-n producer counter. Producer thread0 adds 1 after its
// phase-3 sc1 stores drain; consumer wave0 spins flag[n] >= 64*s. The 4 n-cohorts
// are fully decoupled; the write-once ring makes any drift WAR-safe.
__global__ __launch_bounds__(NT) void fused_all(
    const __hip_bfloat16* __restrict__ Wimg,
    __hip_bfloat16* __restrict__ ring,      // NRING buffers (virgin mode)
    __hip_bfloat16* __restrict__ carryA,    // fallback ping-pong
    __hip_bfloat16* __restrict__ carryB,
    const float* __restrict__ bias,
    const float* fea,            // no restrict: resid aliases out in pass 2
    float* out,
    unsigned* sync,
    int virgin)
{
    __shared__ __hip_bfloat16 Wl[64 * 1024];   // 128 KB, fragment-order
    __shared__ float zone[2][BO][SLDS];        // 25.9 KB reduce/transpose zone

    const int id = blockIdx.x;
    const int og = id & 63;        // id%8 -> XCD
    const int n  = id >> 6;        // 0..3
    const int o0 = og * BO;
    const int j0 = n * W_DIM;
    unsigned* flagn = sync + 64 + n * 64;

    const int tid  = threadIdx.x;
    const int wv   = tid >> 6;
    const int lane = tid & 63;
    const int c16  = lane & 15;
    const int q    = lane >> 4;
    const int jt   = wv % 3;       // j-tile (32 rows)
    const int kq   = wv / 3;       // K quarter (512)

    // ---- stage W slice once: 128 segments x 1 KB, linear copy ----
    for (int sg = wv; sg < 128; sg += 12)
        gload_lds16(Wimg + (size_t)og * 65536 + sg * 512 + lane * 8, Wl + sg * 512);

    // ---- hoisted addressing ----
    // A rows: j0 + jt*32 + ji*16 + c16; cols: kq*512 + kk*32 + q*8
    const size_t arow = (size_t)(j0 + jt * 32 + c16) * C_DIM + kq * 512 + q * 8;
    // B: fragment blocks, lane-linear; global kk = kq*16 + kk
    const __hip_bfloat16* Wb = Wl + kq * 16384 + lane * 8;

    // phase 2 (out store): thread -> (o_l, 4 consecutive w)
    const int oL = tid / 24;
    const int wq = tid % 24;
    const int w2 = wq * 4;
    const float bo = bias[o0 + oL];
    const size_t obase0 = (size_t)(n * C_DIM + o0 + oL) * HW + w2;

    // phase 3 (carry store): thread -> (w row, 4 consecutive o)
    const int wr = tid >> 3;       // 0..95
    const int oq = tid & 7;        // 0..7
    const size_t cidx = (size_t)(j0 + wr) * C_DIM + o0 + oq * 4;

    __syncthreads();   // staged W visible

    unsigned target = 0;
    for (int s = 0; s < NSTEP; ++s) {
        const int h = (s < H_DIM - 1) ? (s + 1) : (2 * H_DIM - 3 - s);  // 1..47, 46..0
        const float* resid = (s < H_DIM - 1) ? fea : out;
        const __hip_bfloat16* csrc;
        __hip_bfloat16*       cdst;
        if (virgin) { csrc = ring + (size_t)s * CE; cdst = ring + (size_t)(s + 1) * CE; }
        else        { csrc = (s & 1) ? carryB : carryA; cdst = (s & 1) ? carryA : carryB; }

        // ---- consumer gate (virgin): wait for all 64 producers of this n ----
        if (virgin && s > 0) {
            if (wv == 0) {
                const unsigned tgt = 64u * (unsigned)s;
                while (__hip_atomic_load(flagn, __ATOMIC_RELAXED, __HIP_MEMORY_SCOPE_AGENT) < tgt)
                    __builtin_amdgcn_s_sleep(2);
            }
            __syncthreads();
        }

        // prefetch residual before compute (latency hides under MFMA loop)
        const floatx4 rv = *(const floatx4*)(resid + obase0 + (size_t)h * W_DIM);

        const __hip_bfloat16* ap0 = csrc + arow;
        const __hip_bfloat16* ap1 = ap0 + 16 * C_DIM;
        floatx4 a00 = {0.f, 0.f, 0.f, 0.f};
        floatx4 a01 = a00, a10 = a00, a11 = a00;
        #pragma unroll
        for (int kk = 0; kk < 16; ++kk) {
            bf16x8 av0 = *(const bf16x8*)(ap0 + kk * 32);
            bf16x8 av1 = *(const bf16x8*)(ap1 + kk * 32);
            bf16x8 bv0 = *(const bf16x8*)(Wb + kk * 1024);
            bf16x8 bv1 = *(const bf16x8*)(Wb + kk * 1024 + 512);
            a00 = __builtin_amdgcn_mfma_f32_16x16x32_bf16(av0, bv0, a00, 0, 0, 0);
            a01 = __builtin_amdgcn_mfma_f32_16x16x32_bf16(av0, bv1, a01, 0, 0, 0);
            a10 = __builtin_amdgcn_mfma_f32_16x16x32_bf16(av1, bv0, a10, 0, 0, 0);
            a11 = __builtin_amdgcn_mfma_f32_16x16x32_bf16(av1, bv1, a11, 0, 0, 0);
        }

        // ---- two-stage K-reduction in zone (D row(M=j)=q*4+r, col(N=o)=c16) ----
        const int w0 = jt * 32 + q * 4;
        if (kq < 2) {
            *(floatx4*)&zone[kq][c16][w0]           = a00;   // ji=0, oi=0
            *(floatx4*)&zone[kq][16 + c16][w0]      = a01;   // ji=0, oi=1
            *(floatx4*)&zone[kq][c16][w0 + 16]      = a10;   // ji=1, oi=0
            *(floatx4*)&zone[kq][16 + c16][w0 + 16] = a11;   // ji=1, oi=1
        }
        __syncthreads();
        if (kq >= 2) {
            const int z = kq - 2;
            *(floatx4*)&zone[z][c16][w0]           += a00;
            *(floatx4*)&zone[z][16 + c16][w0]      += a01;
            *(floatx4*)&zone[z][c16][w0 + 16]      += a10;
            *(floatx4*)&zone[z][16 + c16][w0 + 16] += a11;
        }
        __syncthreads();

        // ---- phase 2: sum halves, bias+relu+residual, coalesced out store ----
        {
            const size_t ob = obase0 + (size_t)h * W_DIM;
            floatx4 z0 = *(const floatx4*)&zone[0][oL][w2];
            floatx4 z1 = *(const floatx4*)&zone[1][oL][w2];
            floatx4 va;
            #pragma unroll
            for (int e = 0; e < 4; ++e)
                va[e] = fmaxf(z0[e] + z1[e] + bo, 0.f) + rv[e];
            *(floatx4*)(out + ob) = va;
            *(floatx4*)&zone[0][oL][w2] = va;   // final values for the transpose
        }
        __syncthreads();

        // ---- phase 3: transpose to carry[j][o], coalesced 8B sc1 stores ----
        {
            alignas(8) __hip_bfloat16 hb[4];
            #pragma unroll
            for (int k = 0; k < 4; ++k)
                hb[k] = __float2bfloat16(zone[0][oq * 4 + k][wr]);
            store8_sc1(cdst + cidx, *(const intx2*)hb);
            asm volatile("s_waitcnt vmcnt(0)" ::: "memory");  // sc1 acked at MALL
        }

        // ---- producer signal / fallback barrier ----
        if (virgin) {
            __syncthreads();   // all waves' stores drained
            if (tid == 0 && s + 1 < NSTEP)
                __hip_atomic_fetch_add(flagn, 1u, __ATOMIC_RELAXED, __HIP_MEMORY_SCOPE_AGENT);
        } else {
            target += NB;
            if (s + 1 < NSTEP) gbar(sync, target);
        }
    }
}

extern "C" void kernel_launch(void* const* d_in, const int* in_sizes, int n_in,
                              void* d_out, int out_size, void* d_ws, size_t ws_size,
                              hipStream_t stream) {
    const float* fea = (const float*)d_in[0];
    const float* W   = (const float*)d_in[1];
    const float* b   = (const float*)d_in[2];
    float* out = (float*)d_out;

    __hip_bfloat16* Wimg   = (__hip_bfloat16*)d_ws;                 // 8 MB
    __hip_bfloat16* carryA = Wimg + (size_t)C_DIM * C_DIM;          // 1.5 MB
    __hip_bfloat16* carryB = carryA + (size_t)CE;                   // 1.5 MB
    unsigned* sync = (unsigned*)(carryB + (size_t)CE);              // 4 KB
    __hip_bfloat16* ring   = (__hip_bfloat16*)((char*)sync + 4096);

    const size_t need = ((size_t)C_DIM * C_DIM + 2 * (size_t)CE) * 2 + 4096
                      + (size_t)NRING * CE * 2;
    const int virgin = (ws_size >= need) ? 1 : 0;
    __hip_bfloat16* carry0 = virgin ? ring : carryA;

    hipLaunchKernelGGL(pack_w, dim3((64 * BO * C_DIM) / 256), dim3(256), 0, stream, W, Wimg);
    hipLaunchKernelGGL(init_carry, dim3((N_DIM * C_DIM * W_DIM) / 256), dim3(256), 0, stream,
                       fea, out, carry0, sync);

    void* args[] = { (void*)&Wimg, (void*)&ring, (void*)&carryA, (void*)&carryB,
                     (void*)&b, (void*)&fea, (void*)&out, (void*)&sync, (void*)&virgin };
    hipLaunchCooperativeKernel(fused_all, dim3(NB), dim3(NT), args, 0, stream);
}